// Round 1
// baseline (454.750 us; speedup 1.0000x reference)
//
#include <hip/hip_runtime.h>
#include <hip/hip_bf16.h>

// B=2 H=16 S=2048 D=64, causal. Output = context (B,H,S,D) ++ attention (B,H,S,S), fp32.

constexpr int SEQ = 2048;
constexpr int HD  = 64;
constexpr int NHEADS = 32;   // B*H
constexpr int QT  = 64;      // q-tile rows per block (also k-tile width)
constexpr int NT  = SEQ / QT;

typedef __bf16 bf16x8 __attribute__((ext_vector_type(8)));
typedef unsigned short u16x8 __attribute__((ext_vector_type(8)));
typedef unsigned short u16x4 __attribute__((ext_vector_type(4)));
typedef float f32x4 __attribute__((ext_vector_type(4)));

__device__ __forceinline__ unsigned short f2bf(float x) {
  unsigned u = __builtin_bit_cast(unsigned, x);
  return (unsigned short)((u + 0x7fffu + ((u >> 16) & 1u)) >> 16);  // RNE
}

__launch_bounds__(256, 4)
__global__ void attn_kernel(const float* __restrict__ Qg,
                            const float* __restrict__ Kg,
                            const float* __restrict__ Vg,
                            float* __restrict__ out) {
  const int qt = blockIdx.x;
  const int bh = blockIdx.y;
  const int t  = threadIdx.x;
  const int l  = t & 63;
  const int w  = t >> 6;        // wave 0..3, owns q-rows w*16..w*16+15
  const int l16 = l & 15;
  const int lg  = l >> 4;       // 0..3

  __shared__ __align__(16) unsigned short Qs[QT * HD];
  __shared__ __align__(16) unsigned short Ks[QT * HD];
  __shared__ __align__(16) unsigned short Vs[QT * HD];     // [key][d], bit4/5 XOR
  __shared__ __align__(16) unsigned short Ps[4][16 * QT];  // per-wave P strip

  const size_t hoff = (size_t)bh * SEQ * HD;
  const float* Qh = Qg + hoff;
  const float* Kh = Kg + hoff;
  const float* Vh = Vg + hoff;
  float* ctx = out + hoff;
  float* att = out + (size_t)NHEADS * SEQ * HD + (size_t)bh * SEQ * SEQ;

  const int qbase = qt * QT;

  // ---- zero-fill masked (upper-triangle) attention columns; fire-and-forget ----
  {
    const int zc0 = (qt + 1) * QT;
    const int nz4 = (SEQ - zc0) >> 2;
    for (int r = 0; r < QT; ++r) {
      float* rowp = att + (size_t)(qbase + r) * SEQ + zc0;
      for (int c = t; c < nz4; c += 256) {
        *(f32x4*)(rowp + 4 * c) = (f32x4){0.f, 0.f, 0.f, 0.f};
      }
    }
  }

  // staging: 64x64 fp32 tile -> bf16 LDS. f = t+256j: row=f>>4, c4=f&15 (coalesced 1KB/wave)
  auto stage_qk = [&](const float* src, unsigned short* dst) {
    #pragma unroll
    for (int j = 0; j < 4; ++j) {
      const int f = t + 256 * j;
      const int r = f >> 4, c4 = f & 15;
      f32x4 v = *(const f32x4*)(src + (size_t)r * HD + 4 * c4);
      const int idx = (r * 64 + 4 * c4) ^ ((r & 7) << 3);   // b128-read swizzle
      u16x4 b = { f2bf(v.x), f2bf(v.y), f2bf(v.z), f2bf(v.w) };
      *(u16x4*)(&dst[idx]) = b;
    }
  };
  auto stage_v = [&](const float* src) {
    #pragma unroll
    for (int j = 0; j < 4; ++j) {
      const int f = t + 256 * j;
      const int r = f >> 4, c4 = f & 15;
      f32x4 v = *(const f32x4*)(src + (size_t)r * HD + 4 * c4);
      const int idx = (r * 64 + 4 * c4) ^ (((r >> 3) & 3) << 4);  // u16-gather swizzle
      u16x4 b = { f2bf(v.x), f2bf(v.y), f2bf(v.z), f2bf(v.w) };
      *(u16x4*)(&Vs[idx]) = b;
    }
  };

  stage_qk(Qh + (size_t)qbase * HD, Qs);
  __syncthreads();

  // preload Q A-fragments (row = l%16 within wave strip, k = 8*(l/16)+j per 32-wide kstep)
  bf16x8 aq[2];
  #pragma unroll
  for (int ks = 0; ks < 2; ++ks) {
    const int qr = w * 16 + l16;
    const int d0 = ks * 32 + lg * 8;
    const int idx = (qr * 64 + d0) ^ ((qr & 7) << 3);
    aq[ks] = __builtin_bit_cast(bf16x8, *(const u16x8*)(&Qs[idx]));
  }

  const float sc = 0.125f;  // 1/sqrt(64)

  // ================= phase 1: row sums of exp(scores) =================
  float sums[4] = {0.f, 0.f, 0.f, 0.f};
  for (int kt = 0; kt <= qt; ++kt) {
    __syncthreads();
    stage_qk(Kh + (size_t)(kt * QT) * HD, Ks);
    __syncthreads();
    const int kb = kt * QT;
    #pragma unroll
    for (int ct = 0; ct < 4; ++ct) {
      f32x4 acc = {0.f, 0.f, 0.f, 0.f};
      #pragma unroll
      for (int ks = 0; ks < 2; ++ks) {
        const int kr = ct * 16 + l16;
        const int d0 = ks * 32 + lg * 8;
        const int idx = (kr * 64 + d0) ^ ((kr & 7) << 3);
        bf16x8 bk = __builtin_bit_cast(bf16x8, *(const u16x8*)(&Ks[idx]));
        acc = __builtin_amdgcn_mfma_f32_16x16x32_bf16(aq[ks], bk, acc, 0, 0, 0);
      }
      const int kg = kb + ct * 16 + l16;
      #pragma unroll
      for (int r = 0; r < 4; ++r) {
        const int qg = qbase + w * 16 + lg * 4 + r;
        float p = (kg <= qg) ? __expf(acc[r] * sc) : 0.f;
        sums[r] += p;
      }
    }
  }
  // reduce across the 16 lanes sharing each row (xor over low 4 lane bits)
  #pragma unroll
  for (int r = 0; r < 4; ++r) {
    float s = sums[r];
    s += __shfl_xor(s, 1);
    s += __shfl_xor(s, 2);
    s += __shfl_xor(s, 4);
    s += __shfl_xor(s, 8);
    sums[r] = 1.f / s;   // now holds inv row-sum for row lg*4+r of this wave
  }

  // ================= phase 2: write P, accumulate O = P·V =================
  f32x4 oacc[4];
  #pragma unroll
  for (int ct = 0; ct < 4; ++ct) oacc[ct] = (f32x4){0.f, 0.f, 0.f, 0.f};

  for (int kt = 0; kt <= qt; ++kt) {
    __syncthreads();
    stage_qk(Kh + (size_t)(kt * QT) * HD, Ks);
    stage_v(Vh + (size_t)(kt * QT) * HD);
    __syncthreads();
    const int kb = kt * QT;

    // recompute scores, normalize, write attention + stage P (bf16) for PV
    #pragma unroll
    for (int ct = 0; ct < 4; ++ct) {
      f32x4 acc = {0.f, 0.f, 0.f, 0.f};
      #pragma unroll
      for (int ks = 0; ks < 2; ++ks) {
        const int kr = ct * 16 + l16;
        const int d0 = ks * 32 + lg * 8;
        const int idx = (kr * 64 + d0) ^ ((kr & 7) << 3);
        bf16x8 bk = __builtin_bit_cast(bf16x8, *(const u16x8*)(&Ks[idx]));
        acc = __builtin_amdgcn_mfma_f32_16x16x32_bf16(aq[ks], bk, acc, 0, 0, 0);
      }
      const int kg = kb + ct * 16 + l16;
      #pragma unroll
      for (int r = 0; r < 4; ++r) {
        const int qg = qbase + w * 16 + lg * 4 + r;
        float p = (kg <= qg) ? __expf(acc[r] * sc) * sums[r] : 0.f;
        att[(size_t)qg * SEQ + kg] = p;
        const int qr = lg * 4 + r;
        Ps[w][(qr * 64 + ct * 16 + l16) ^ ((qr & 7) << 3)] = f2bf(p);
      }
    }

    // PV: A = P strip (wave-local), B = V gathered per-element (conflict-free via swizzle)
    #pragma unroll
    for (int ct = 0; ct < 4; ++ct) {
      #pragma unroll
      for (int ks = 0; ks < 2; ++ks) {
        const int key0 = ks * 32 + lg * 8;
        const int pidx = (l16 * 64 + key0) ^ ((l16 & 7) << 3);
        bf16x8 pa = __builtin_bit_cast(bf16x8, *(const u16x8*)(&Ps[w][pidx]));
        bf16x8 bv;
        const int dcol = ct * 16 + l16;
        const int xorv = ((key0 >> 3) & 3) << 4;
        #pragma unroll
        for (int j = 0; j < 8; ++j) {
          bv[j] = __builtin_bit_cast(__bf16, Vs[((key0 + j) * 64 + dcol) ^ xorv]);
        }
        oacc[ct] = __builtin_amdgcn_mfma_f32_16x16x32_bf16(pa, bv, oacc[ct], 0, 0, 0);
      }
    }
  }

  // ---- write context ----
  #pragma unroll
  for (int ct = 0; ct < 4; ++ct) {
    #pragma unroll
    for (int r = 0; r < 4; ++r) {
      const int qg = qbase + w * 16 + lg * 4 + r;
      ctx[(size_t)qg * HD + ct * 16 + l16] = oacc[ct][r];
    }
  }
}

extern "C" void kernel_launch(void* const* d_in, const int* in_sizes, int n_in,
                              void* d_out, int out_size, void* d_ws, size_t ws_size,
                              hipStream_t stream) {
  const float* Q = (const float*)d_in[0];
  const float* K = (const float*)d_in[1];
  const float* V = (const float*)d_in[2];
  float* out = (float*)d_out;
  dim3 grid(NT, NHEADS);
  attn_kernel<<<grid, dim3(256), 0, stream>>>(Q, K, V, out);
}

// Round 2
// 453.814 us; speedup vs baseline: 1.0021x; 1.0021x over previous
//
#include <hip/hip_runtime.h>
#include <hip/hip_bf16.h>

// B=2 H=16 S=2048 D=64, causal. Output = context (B,H,S,D) ++ attention (B,H,S,S), fp32.

constexpr int SEQ = 2048;
constexpr int HD  = 64;
constexpr int NHEADS = 32;   // B*H
constexpr int QT  = 64;      // q-tile rows per block (also k-tile width)
constexpr int NT  = SEQ / QT;

typedef __bf16 bf16x8 __attribute__((ext_vector_type(8)));
typedef unsigned short u16x8 __attribute__((ext_vector_type(8)));
typedef unsigned short u16x4 __attribute__((ext_vector_type(4)));
typedef float f32x4 __attribute__((ext_vector_type(4)));

__device__ __forceinline__ unsigned short f2bf(float x) {
  unsigned u = __builtin_bit_cast(unsigned, x);
  return (unsigned short)((u + 0x7fffu + ((u >> 16) & 1u)) >> 16);  // RNE
}

__launch_bounds__(256, 4)
__global__ void attn_kernel(const float* __restrict__ Qg,
                            const float* __restrict__ Kg,
                            const float* __restrict__ Vg,
                            float* __restrict__ out) {
  const int bx = blockIdx.x;
  // heavy/light pairing: adjacent dispatches alternate big/small causal rows
  const int qt = (bx & 1) ? (NT - 1 - (bx >> 1)) : (bx >> 1);
  const int bh = blockIdx.y;
  const int t  = threadIdx.x;
  const int l  = t & 63;
  const int w  = t >> 6;        // wave 0..3, owns q-rows w*16..w*16+15
  const int l16 = l & 15;
  const int lg  = l >> 4;       // 0..3

  __shared__ __align__(16) unsigned short Qs[QT * HD];
  __shared__ __align__(16) unsigned short Ks[QT * HD];
  __shared__ __align__(16) unsigned short Vs[QT * HD];     // [key][d], bit4/5 XOR by key
  __shared__ __align__(16) unsigned short Ps[4][16 * QT];  // per-wave P strip [q=16][k=64]

  const size_t hoff = (size_t)bh * SEQ * HD;
  const float* Qh = Qg + hoff;
  const float* Kh = Kg + hoff;
  const float* Vh = Vg + hoff;
  float* ctx = out + hoff;
  float* att = out + (size_t)NHEADS * SEQ * HD + (size_t)bh * SEQ * SEQ;

  const int qbase = qt * QT;
  const int qg = qbase + w * 16 + l16;   // this lane's q-row (S^T layout: col=lane&15)
  float* attrow = att + (size_t)qg * SEQ;

  // ---- zero-fill masked (upper-triangle) attention columns; fire-and-forget ----
  {
    const int zc0 = (qt + 1) * QT;
    const int nz4 = (SEQ - zc0) >> 2;
    for (int r = 0; r < QT; ++r) {
      float* rowp = att + (size_t)(qbase + r) * SEQ + zc0;
      for (int c = t; c < nz4; c += 256) {
        *(f32x4*)(rowp + 4 * c) = (f32x4){0.f, 0.f, 0.f, 0.f};
      }
    }
  }

  // ---- staging helpers: 64x64 fp32 tile; thread t covers (row=f>>4, col4=f&15) ----
  auto load_tile = [&](const float* src, f32x4* reg) {
    #pragma unroll
    for (int j = 0; j < 4; ++j) {
      const int f = t + 256 * j;
      reg[j] = *(const f32x4*)(src + (size_t)(f >> 4) * HD + 4 * (f & 15));
    }
  };
  auto write_qk = [&](const f32x4* reg, unsigned short* dst) {
    #pragma unroll
    for (int j = 0; j < 4; ++j) {
      const int f = t + 256 * j;
      const int r = f >> 4, c4 = f & 15;
      const int idx = (r * 64 + 4 * c4) ^ ((r & 7) << 3);   // b128-read swizzle
      u16x4 b = { f2bf(reg[j].x), f2bf(reg[j].y), f2bf(reg[j].z), f2bf(reg[j].w) };
      *(u16x4*)(&dst[idx]) = b;
    }
  };
  auto write_v = [&](const f32x4* reg) {
    #pragma unroll
    for (int j = 0; j < 4; ++j) {
      const int f = t + 256 * j;
      const int r = f >> 4, c4 = f & 15;
      const int idx = (r * 64 + 4 * c4) ^ (((r >> 3) & 3) << 4);  // u16-gather swizzle
      u16x4 b = { f2bf(reg[j].x), f2bf(reg[j].y), f2bf(reg[j].z), f2bf(reg[j].w) };
      *(u16x4*)(&Vs[idx]) = b;
    }
  };

  // ---- stage Q once; preload Q B-fragments ----
  {
    f32x4 qreg[4];
    load_tile(Qh + (size_t)qbase * HD, qreg);
    write_qk(qreg, Qs);
  }
  __syncthreads();

  bf16x8 aq[2];   // B-frag for swapped QK^T: Q[q=l16 within strip][d=(l>>4)*8+j (+32ks)]
  #pragma unroll
  for (int ks = 0; ks < 2; ++ks) {
    const int qr = w * 16 + l16;
    const int d0 = ks * 32 + lg * 8;
    const int idx = (qr * 64 + d0) ^ ((qr & 7) << 3);
    aq[ks] = __builtin_bit_cast(bf16x8, *(const u16x8*)(&Qs[idx]));
  }

  const float sc = 0.125f;  // 1/sqrt(64)

  // ================= phase 1: row sums of exp(scores) =================
  float rsum = 0.f;
  {
    f32x4 kreg[4];
    load_tile(Kh, kreg);
    write_qk(kreg, Ks);
    __syncthreads();
    for (int kt = 0; kt <= qt; ++kt) {
      if (kt < qt) load_tile(Kh + (size_t)(kt + 1) * QT * HD, kreg);  // prefetch next
      const int kb = kt * QT;
      #pragma unroll
      for (int ct = 0; ct < 4; ++ct) {
        f32x4 acc = {0.f, 0.f, 0.f, 0.f};
        #pragma unroll
        for (int ks = 0; ks < 2; ++ks) {
          const int kr = ct * 16 + l16;
          const int d0 = ks * 32 + lg * 8;
          const int idx = (kr * 64 + d0) ^ ((kr & 7) << 3);
          bf16x8 bk = __builtin_bit_cast(bf16x8, *(const u16x8*)(&Ks[idx]));
          acc = __builtin_amdgcn_mfma_f32_16x16x32_bf16(bk, aq[ks], acc, 0, 0, 0);  // S^T
        }
        const int kg0 = kb + ct * 16 + lg * 4;
        #pragma unroll
        for (int r = 0; r < 4; ++r) {
          float e = __expf(acc[r] * sc);
          rsum += (kg0 + r <= qg) ? e : 0.f;
        }
      }
      __syncthreads();
      if (kt < qt) write_qk(kreg, Ks);
      __syncthreads();
    }
  }
  // reduce across the 4 lg-groups holding the same q-row (l16)
  rsum += __shfl_xor(rsum, 16);
  rsum += __shfl_xor(rsum, 32);
  const float inv = 1.f / rsum;

  // ================= phase 2: write P, accumulate O = P·V =================
  f32x4 oacc[4];
  #pragma unroll
  for (int ct = 0; ct < 4; ++ct) oacc[ct] = (f32x4){0.f, 0.f, 0.f, 0.f};

  {
    f32x4 kreg[4], vreg[4];
    load_tile(Kh, kreg);
    load_tile(Vh, vreg);
    write_qk(kreg, Ks);
    write_v(vreg);
    __syncthreads();
    for (int kt = 0; kt <= qt; ++kt) {
      if (kt < qt) {
        load_tile(Kh + (size_t)(kt + 1) * QT * HD, kreg);  // prefetch next tiles
        load_tile(Vh + (size_t)(kt + 1) * QT * HD, vreg);
      }
      const int kb = kt * QT;

      // QK^T (swapped) -> normalize -> float4 att store + Ps stage
      #pragma unroll
      for (int ct = 0; ct < 4; ++ct) {
        f32x4 acc = {0.f, 0.f, 0.f, 0.f};
        #pragma unroll
        for (int ks = 0; ks < 2; ++ks) {
          const int kr = ct * 16 + l16;
          const int d0 = ks * 32 + lg * 8;
          const int idx = (kr * 64 + d0) ^ ((kr & 7) << 3);
          bf16x8 bk = __builtin_bit_cast(bf16x8, *(const u16x8*)(&Ks[idx]));
          acc = __builtin_amdgcn_mfma_f32_16x16x32_bf16(bk, aq[ks], acc, 0, 0, 0);
        }
        const int kg0 = kb + ct * 16 + lg * 4;
        f32x4 p;
        #pragma unroll
        for (int r = 0; r < 4; ++r) {
          float e = __expf(acc[r] * sc) * inv;
          p[r] = (kg0 + r <= qg) ? e : 0.f;
        }
        *(f32x4*)(attrow + kg0) = p;   // dwordx4, 4 consecutive k-columns
        u16x4 pb = { f2bf(p[0]), f2bf(p[1]), f2bf(p[2]), f2bf(p[3]) };
        const int pidx = (l16 * 64 + ct * 16 + lg * 4) ^ ((l16 & 7) << 3);
        *(u16x4*)(&Ps[w][pidx]) = pb;
      }

      // PV (swapped): A = V^T (per-element gather, conflict-free), B = P^T strip
      #pragma unroll
      for (int ct = 0; ct < 4; ++ct) {
        #pragma unroll
        for (int ks = 0; ks < 2; ++ks) {
          const int key0 = ks * 32 + lg * 8;
          const int pidx = (l16 * 64 + key0) ^ ((l16 & 7) << 3);
          bf16x8 pa = __builtin_bit_cast(bf16x8, *(const u16x8*)(&Ps[w][pidx]));
          bf16x8 av;
          const int dcol = ct * 16 + l16;
          const int xorv = ((key0 >> 3) & 3) << 4;
          #pragma unroll
          for (int j = 0; j < 8; ++j) {
            av[j] = __builtin_bit_cast(__bf16, Vs[((key0 + j) * 64 + dcol) ^ xorv]);
          }
          oacc[ct] = __builtin_amdgcn_mfma_f32_16x16x32_bf16(av, pa, oacc[ct], 0, 0, 0);
        }
      }

      __syncthreads();
      if (kt < qt) {
        write_qk(kreg, Ks);
        write_v(vreg);
      }
      __syncthreads();
    }
  }

  // ---- write context: O[q=l16][d = ct*16 + lg*4 + r] -> dwordx4 ----
  #pragma unroll
  for (int ct = 0; ct < 4; ++ct) {
    *(f32x4*)(ctx + (size_t)qg * HD + ct * 16 + lg * 4) = oacc[ct];
  }
}

extern "C" void kernel_launch(void* const* d_in, const int* in_sizes, int n_in,
                              void* d_out, int out_size, void* d_ws, size_t ws_size,
                              hipStream_t stream) {
  const float* Q = (const float*)d_in[0];
  const float* K = (const float*)d_in[1];
  const float* V = (const float*)d_in[2];
  float* out = (float*)d_out;
  dim3 grid(NT, NHEADS);
  attn_kernel<<<grid, dim3(256), 0, stream>>>(Q, K, V, out);
}

// Round 3
// 205.737 us; speedup vs baseline: 2.2103x; 2.2058x over previous
//
#include <hip/hip_runtime.h>
#include <hip/hip_bf16.h>

// B=2 H=16 S=2048 D=64, causal. Output = context (B,H,S,D) ++ attention (B,H,S,S), fp32.
// Uniform-work blocks: block (pi, bh) handles q-tiles pi and 31-pi  => 33 k-iters/phase each.

constexpr int SEQ = 2048;
constexpr int HD  = 64;
constexpr int NHEADS = 32;   // B*H
constexpr int QT  = 64;      // q-tile rows (also k-tile width)
constexpr int NT  = SEQ / QT;

typedef __bf16 bf16x8 __attribute__((ext_vector_type(8)));
typedef unsigned short u16x8 __attribute__((ext_vector_type(8)));
typedef unsigned short u16x4 __attribute__((ext_vector_type(4)));
typedef float f32x4 __attribute__((ext_vector_type(4)));

__device__ __forceinline__ unsigned short f2bf(float x) {
  unsigned u = __builtin_bit_cast(unsigned, x);
  return (unsigned short)((u + 0x7fffu + ((u >> 16) & 1u)) >> 16);  // RNE
}
__device__ __forceinline__ float bf2f(unsigned short b) {
  return __builtin_bit_cast(float, (unsigned)b << 16);
}

__launch_bounds__(256, 2)
__global__ void attn_kernel(const float* __restrict__ Qg,
                            const float* __restrict__ Kg,
                            const float* __restrict__ Vg,
                            float* __restrict__ out) {
  const int pi = blockIdx.x;    // 0..15 : pair index
  const int bh = blockIdx.y;
  const int t  = threadIdx.x;
  const int l  = t & 63;
  const int w  = t >> 6;        // wave 0..3, owns q-rows w*16..w*16+15
  const int l16 = l & 15;
  const int lg  = l >> 4;       // 0..3

  __shared__ __align__(16) unsigned short Qs[QT * HD];
  __shared__ __align__(16) unsigned short Ks[QT * HD];
  __shared__ __align__(16) unsigned short Vs[QT * HD];     // [key][d], bit4/5 XOR by key
  __shared__ __align__(16) unsigned short Ps[4][16 * QT];  // per-wave P strip [q=16][k=64]

  const size_t hoff = (size_t)bh * SEQ * HD;
  const float* Qh = Qg + hoff;
  const float* Kh = Kg + hoff;
  const float* Vh = Vg + hoff;
  float* ctx = out + hoff;
  float* att = out + (size_t)NHEADS * SEQ * HD + (size_t)bh * SEQ * SEQ;

  // ---- staging helpers: 64x64 fp32 tile; thread t covers (row=f>>4, col4=f&15) ----
  auto load_tile = [&](const float* src, f32x4* reg) {
    #pragma unroll
    for (int j = 0; j < 4; ++j) {
      const int f = t + 256 * j;
      reg[j] = *(const f32x4*)(src + (size_t)(f >> 4) * HD + 4 * (f & 15));
    }
  };
  auto write_qk = [&](const f32x4* reg, unsigned short* dst) {
    #pragma unroll
    for (int j = 0; j < 4; ++j) {
      const int f = t + 256 * j;
      const int r = f >> 4, c4 = f & 15;
      const int idx = (r * 64 + 4 * c4) ^ ((r & 7) << 3);   // b128-read swizzle
      u16x4 b = { f2bf(reg[j].x), f2bf(reg[j].y), f2bf(reg[j].z), f2bf(reg[j].w) };
      *(u16x4*)(&dst[idx]) = b;
    }
  };
  auto write_v = [&](const f32x4* reg) {
    #pragma unroll
    for (int j = 0; j < 4; ++j) {
      const int f = t + 256 * j;
      const int r = f >> 4, c4 = f & 15;
      const int idx = (r * 64 + 4 * c4) ^ (((r >> 3) & 3) << 4);  // u16-gather swizzle
      u16x4 b = { f2bf(reg[j].x), f2bf(reg[j].y), f2bf(reg[j].z), f2bf(reg[j].w) };
      *(u16x4*)(&Vs[idx]) = b;
    }
  };

  const float sc = 0.125f;  // 1/sqrt(64)

  for (int half = 0; half < 2; ++half) {
    const int qt = half ? (NT - 1 - pi) : pi;
    const int qbase = qt * QT;
    const int qg = qbase + w * 16 + l16;   // this lane's q-row (S^T layout)

    __syncthreads();   // previous half's LDS reads fully retired

    // ---- zero-fill masked columns (nontemporal, full-line coalesced) ----
    {
      const int zc0 = (qt + 1) * QT;
      const int nz4 = (SEQ - zc0) >> 2;
      for (int r = 0; r < QT; ++r) {
        float* rowp = att + (size_t)(qbase + r) * SEQ + zc0;
        for (int c = t; c < nz4; c += 256) {
          __builtin_nontemporal_store((f32x4){0.f, 0.f, 0.f, 0.f}, (f32x4*)(rowp + 4 * c));
        }
      }
    }

    // ---- stage Q; preload Q B-fragments ----
    {
      f32x4 qreg[4];
      load_tile(Qh + (size_t)qbase * HD, qreg);
      write_qk(qreg, Qs);
    }
    __syncthreads();

    bf16x8 aq[2];
    #pragma unroll
    for (int ks = 0; ks < 2; ++ks) {
      const int qr = w * 16 + l16;
      const int d0 = ks * 32 + lg * 8;
      const int idx = (qr * 64 + d0) ^ ((qr & 7) << 3);
      aq[ks] = __builtin_bit_cast(bf16x8, *(const u16x8*)(&Qs[idx]));
    }

    // ================= phase 1: row sums of exp(scores) =================
    float rsum = 0.f;
    {
      f32x4 kreg[4];
      load_tile(Kh, kreg);
      write_qk(kreg, Ks);
      __syncthreads();
      for (int kt = 0; kt <= qt; ++kt) {
        if (kt < qt) load_tile(Kh + (size_t)(kt + 1) * QT * HD, kreg);  // prefetch
        const int kb = kt * QT;
        #pragma unroll
        for (int ct = 0; ct < 4; ++ct) {
          f32x4 acc = {0.f, 0.f, 0.f, 0.f};
          #pragma unroll
          for (int ks = 0; ks < 2; ++ks) {
            const int kr = ct * 16 + l16;
            const int d0 = ks * 32 + lg * 8;
            const int idx = (kr * 64 + d0) ^ ((kr & 7) << 3);
            bf16x8 bk = __builtin_bit_cast(bf16x8, *(const u16x8*)(&Ks[idx]));
            acc = __builtin_amdgcn_mfma_f32_16x16x32_bf16(bk, aq[ks], acc, 0, 0, 0);  // S^T
          }
          const int kg0 = kb + ct * 16 + lg * 4;
          #pragma unroll
          for (int r = 0; r < 4; ++r) {
            float e = __expf(acc[r] * sc);
            rsum += (kg0 + r <= qg) ? e : 0.f;
          }
        }
        __syncthreads();
        if (kt < qt) write_qk(kreg, Ks);
        __syncthreads();
      }
    }
    rsum += __shfl_xor(rsum, 16);
    rsum += __shfl_xor(rsum, 32);
    const float inv = 1.f / rsum;

    // ================= phase 2: P -> att + O = P·V =================
    f32x4 oacc[4];
    #pragma unroll
    for (int ct = 0; ct < 4; ++ct) oacc[ct] = (f32x4){0.f, 0.f, 0.f, 0.f};

    {
      f32x4 kreg[4], vreg[4];
      load_tile(Kh, kreg);
      load_tile(Vh, vreg);
      write_qk(kreg, Ks);
      write_v(vreg);
      __syncthreads();
      for (int kt = 0; kt <= qt; ++kt) {
        if (kt < qt) {
          load_tile(Kh + (size_t)(kt + 1) * QT * HD, kreg);  // prefetch
          load_tile(Vh + (size_t)(kt + 1) * QT * HD, vreg);
        }
        const int kb = kt * QT;

        // QK^T (swapped) -> normalized bf16 P into Ps
        #pragma unroll
        for (int ct = 0; ct < 4; ++ct) {
          f32x4 acc = {0.f, 0.f, 0.f, 0.f};
          #pragma unroll
          for (int ks = 0; ks < 2; ++ks) {
            const int kr = ct * 16 + l16;
            const int d0 = ks * 32 + lg * 8;
            const int idx = (kr * 64 + d0) ^ ((kr & 7) << 3);
            bf16x8 bk = __builtin_bit_cast(bf16x8, *(const u16x8*)(&Ks[idx]));
            acc = __builtin_amdgcn_mfma_f32_16x16x32_bf16(bk, aq[ks], acc, 0, 0, 0);
          }
          const int kg0 = kb + ct * 16 + lg * 4;
          u16x4 pb;
          #pragma unroll
          for (int r = 0; r < 4; ++r) {
            float e = __expf(acc[r] * sc) * inv;
            pb[r] = f2bf((kg0 + r <= qg) ? e : 0.f);
          }
          const int pidx = (l16 * 64 + ct * 16 + lg * 4) ^ ((l16 & 7) << 3);
          *(u16x4*)(&Ps[w][pidx]) = pb;
        }

        // PV (swapped): A = V^T (per-element gather), B = P^T strip (wave-local)
        #pragma unroll
        for (int ct = 0; ct < 4; ++ct) {
          #pragma unroll
          for (int ks = 0; ks < 2; ++ks) {
            const int key0 = ks * 32 + lg * 8;
            const int pidx = (l16 * 64 + key0) ^ ((l16 & 7) << 3);
            bf16x8 pa = __builtin_bit_cast(bf16x8, *(const u16x8*)(&Ps[w][pidx]));
            bf16x8 av;
            const int dcol = ct * 16 + l16;
            const int xorv = ((key0 >> 3) & 3) << 4;
            #pragma unroll
            for (int j = 0; j < 8; ++j) {
              av[j] = __builtin_bit_cast(__bf16, Vs[((key0 + j) * 64 + dcol) ^ xorv]);
            }
            oacc[ct] = __builtin_amdgcn_mfma_f32_16x16x32_bf16(av, pa, oacc[ct], 0, 0, 0);
          }
        }

        __syncthreads();   // Ps complete (all waves); Ks/Vs reads retired

        // att copy: full-line coalesced nontemporal stores (4 rows/wave, 256B/row)
        #pragma unroll
        for (int j = 0; j < 4; ++j) {
          const int f = t + 256 * j;
          const int r = f >> 4, c4 = f & 15;
          const int ww = r >> 4, qr = r & 15;
          const int idx = (qr * 64 + 4 * c4) ^ ((qr & 7) << 3);
          u16x4 pb = *(const u16x4*)(&Ps[ww][idx]);
          f32x4 pv = { bf2f(pb[0]), bf2f(pb[1]), bf2f(pb[2]), bf2f(pb[3]) };
          __builtin_nontemporal_store(pv,
              (f32x4*)(att + (size_t)(qbase + r) * SEQ + kb + 4 * c4));
        }

        if (kt < qt) {        // overwrite Ks/Vs for next iter (disjoint from Ps)
          write_qk(kreg, Ks);
          write_v(vreg);
        }
        __syncthreads();
      }
    }

    // ---- write context: O[q=l16][d = ct*16 + lg*4 + r] -> dwordx4 ----
    #pragma unroll
    for (int ct = 0; ct < 4; ++ct) {
      *(f32x4*)(ctx + (size_t)qg * HD + ct * 16 + lg * 4) = oacc[ct];
    }
  }
}

extern "C" void kernel_launch(void* const* d_in, const int* in_sizes, int n_in,
                              void* d_out, int out_size, void* d_ws, size_t ws_size,
                              hipStream_t stream) {
  const float* Q = (const float*)d_in[0];
  const float* K = (const float*)d_in[1];
  const float* V = (const float*)d_in[2];
  float* out = (float*)d_out;
  dim3 grid(NT / 2, NHEADS);
  attn_kernel<<<grid, dim3(256), 0, stream>>>(Q, K, V, out);
}